// Round 1
// baseline (4923.043 us; speedup 1.0000x reference)
//
#include <hip/hip_runtime.h>
#include <cmath>

#define HH 512
#define WW 512
#define NIMG 12
#define RES (HH*WW)
#define NBINS 256

// LDS weight layout per predictor (floats)
#define OWT 0
#define OBT 672
#define OWL 704
#define OW1 800
#define OB1 1824
#define OW2 1856
#define OB2 2880
#define OW3 2912
#define OB3 2944
#define WSTRIDE 2945
#define WTOTAL (3*WSTRIDE)

struct WPtrs {
    const float* wT[3]; const float* bT[3]; const float* wL[3];
    const float* w1[3]; const float* b1[3];
    const float* w2[3]; const float* b2[3];
    const float* w3[3]; const float* b3[3];
};

__global__ __launch_bounds__(256) void codec_main(
    const float* __restrict__ x, WPtrs wp,
    float* __restrict__ sums,            // [0]=sum x^2, [1]=sum delta^2
    unsigned* __restrict__ hist_x,       // [12][256]
    unsigned* __restrict__ hist_d)       // [12][256]
{
    __shared__ float sw[WTOTAL];
    __shared__ unsigned shx[NBINS], shd[NBINS];
    __shared__ float red[8];

    const int tid = threadIdx.x;

    // ---- stage all weights into LDS ----
    for (int p = 0; p < 3; ++p) {
        float* base = sw + p * WSTRIDE;
        for (int k = tid; k < 672;  k += 256) base[OWT + k] = wp.wT[p][k];
        for (int k = tid; k < 96;   k += 256) base[OWL + k] = wp.wL[p][k];
        for (int k = tid; k < 1024; k += 256) base[OW1 + k] = wp.w1[p][k];
        for (int k = tid; k < 1024; k += 256) base[OW2 + k] = wp.w2[p][k];
        if (tid < 32) {
            base[OBT + tid] = wp.bT[p][tid];
            base[OB1 + tid] = wp.b1[p][tid];
            base[OB2 + tid] = wp.b2[p][tid];
            base[OW3 + tid] = wp.w3[p][tid];
        }
        if (tid == 0) base[OB3] = wp.b3[p][0];
    }
    shx[tid] = 0u; shd[tid] = 0u;
    __syncthreads();

    const int img = blockIdx.y;
    const int t = blockIdx.x * 256 + tid;     // pixel index within image
    const int i = t >> 9;                     // row
    const int j = t & (WW - 1);               // col
    const float* __restrict__ X = x + (size_t)img * RES;

    // ---- gather causal patch (zero padded) ----
    float pT[21], pL[3];
    #pragma unroll
    for (int r = 0; r < 3; ++r) {
        const int row = i - 3 + r;
        #pragma unroll
        for (int c = 0; c < 7; ++c) {
            const int col = j - 3 + c;
            pT[r*7 + c] = (row >= 0 && col >= 0 && col < WW) ? X[row*WW + col] : 0.0f;
        }
    }
    #pragma unroll
    for (int k = 0; k < 3; ++k) {
        const int col = j - 3 + k;
        pL[k] = (col >= 0) ? X[i*WW + col] : 0.0f;
    }
    const float xv = X[i*WW + j];

    // ---- three predictors ----
    float pred[3];
    for (int p = 0; p < 3; ++p) {
        const float* wb = sw + p * WSTRIDE;
        float h0[32], h1[32];
        #pragma unroll
        for (int c = 0; c < 32; ++c) {
            float acc = wb[OBT + c];
            #pragma unroll
            for (int k = 0; k < 21; ++k) acc += wb[OWT + c*21 + k] * pT[k];
            #pragma unroll
            for (int k = 0; k < 3;  ++k) acc += wb[OWL + c*3 + k] * pL[k];
            h0[c] = acc >= 0.0f ? acc : 0.01f*acc;
        }
        #pragma unroll
        for (int co = 0; co < 32; ++co) {
            float acc = wb[OB1 + co];
            #pragma unroll
            for (int ci = 0; ci < 32; ++ci) acc += wb[OW1 + co*32 + ci] * h0[ci];
            h1[co] = acc >= 0.0f ? acc : 0.01f*acc;
        }
        #pragma unroll
        for (int co = 0; co < 32; ++co) {
            float acc = wb[OB2 + co];
            #pragma unroll
            for (int ci = 0; ci < 32; ++ci) acc += wb[OW2 + co*32 + ci] * h1[ci];
            h0[co] = acc >= 0.0f ? acc : 0.01f*acc;   // reuse h0 as h2
        }
        float acc = wb[OB3];
        #pragma unroll
        for (int ci = 0; ci < 32; ++ci) acc += wb[OW3 + ci] * h0[ci];
        pred[p] = fminf(fmaxf(acc, -1.0f), 1.0f);
    }

    // ---- median-of-3 predictor + wrap-around residual ----
    const float a = pred[0], b = pred[1], c = pred[2];
    const float med = fmaxf(fminf(a, fmaxf(b, c)), fminf(b, c));
    const float delta = fmodf(xv - med + 1.0f, 2.0f) - 1.0f;

    // ---- histograms (torch.histc semantics: out-of-range excluded) ----
    if (xv >= -1.0f && xv <= 1.0f) {
        int bin = (int)floorf((xv + 1.0f) * 128.0f);
        bin = bin < 0 ? 0 : (bin > 255 ? 255 : bin);
        atomicAdd(&shx[bin], 1u);
    }
    if (delta >= -1.0f && delta <= 1.0f) {
        int bin = (int)floorf((delta + 1.0f) * 128.0f);
        bin = bin < 0 ? 0 : (bin > 255 ? 255 : bin);
        atomicAdd(&shd[bin], 1u);
    }

    // ---- sum-of-squares reduction ----
    float sx = xv * xv, sd = delta * delta;
    #pragma unroll
    for (int off = 32; off > 0; off >>= 1) {
        sx += __shfl_down(sx, off);
        sd += __shfl_down(sd, off);
    }
    const int lane = tid & 63, wv = tid >> 6;
    if (lane == 0) { red[wv] = sx; red[4 + wv] = sd; }
    __syncthreads();
    if (tid == 0) {
        atomicAdd(&sums[0], red[0] + red[1] + red[2] + red[3]);
        atomicAdd(&sums[1], red[4] + red[5] + red[6] + red[7]);
    }
    if (shx[tid]) atomicAdd(&hist_x[img*NBINS + tid], shx[tid]);
    if (shd[tid]) atomicAdd(&hist_d[img*NBINS + tid], shd[tid]);
}

__global__ __launch_bounds__(256) void codec_final(
    const float* __restrict__ sums,
    const unsigned* __restrict__ hist_x,
    const unsigned* __restrict__ hist_d,
    float* __restrict__ out)
{
    __shared__ float red[16];
    const int tid = threadIdx.x;
    float ex = 0.0f, ed = 0.0f;
    const float inv_res = 1.0f / (float)RES;
    for (int k = tid; k < NIMG*NBINS; k += 256) {
        const unsigned hx = hist_x[k];
        const unsigned hd = hist_d[k];
        if (hx) { const float p = (float)hx * inv_res; ex -= p * log2f(p); }
        if (hd) { const float p = (float)hd * inv_res; ed -= p * log2f(p); }
    }
    #pragma unroll
    for (int off = 32; off > 0; off >>= 1) {
        ex += __shfl_down(ex, off);
        ed += __shfl_down(ed, off);
    }
    const int lane = tid & 63, wv = tid >> 6;
    if (lane == 0) { red[wv] = ex; red[8 + wv] = ed; }
    __syncthreads();
    if (tid == 0) {
        const float Ex = red[0] + red[1] + red[2] + red[3];
        const float Ed = red[8] + red[9] + red[10] + red[11];
        const float inv_n = 1.0f / (float)(NIMG * RES);
        out[0] = 255.0f * sqrtf(sums[1] * inv_n);   // loss1 (deltas)
        out[1] = 255.0f * sqrtf(sums[0] * inv_n);   // loss0 (x)
        out[2] = Ex / (8.0f * (float)NIMG);         // invCR0
        out[3] = Ed / (8.0f * (float)NIMG);         // invCR1
    }
}

extern "C" void kernel_launch(void* const* d_in, const int* in_sizes, int n_in,
                              void* d_out, int out_size, void* d_ws, size_t ws_size,
                              hipStream_t stream)
{
    const float* x = (const float*)d_in[0];
    WPtrs wp;
    for (int p = 0; p < 3; ++p) {
        const int b = 1 + 9*p;
        wp.wT[p] = (const float*)d_in[b+0];
        wp.bT[p] = (const float*)d_in[b+1];
        wp.wL[p] = (const float*)d_in[b+2];
        wp.w1[p] = (const float*)d_in[b+3];
        wp.b1[p] = (const float*)d_in[b+4];
        wp.w2[p] = (const float*)d_in[b+5];
        wp.b2[p] = (const float*)d_in[b+6];
        wp.w3[p] = (const float*)d_in[b+7];
        wp.b3[p] = (const float*)d_in[b+8];
    }

    float*    sums   = (float*)d_ws;
    unsigned* hist_x = (unsigned*)((char*)d_ws + 16);
    unsigned* hist_d = hist_x + NIMG*NBINS;
    const size_t zbytes = 16 + (size_t)2*NIMG*NBINS*sizeof(unsigned);
    hipMemsetAsync(d_ws, 0, zbytes, stream);

    dim3 grid(RES/256, NIMG);
    codec_main<<<grid, dim3(256), 0, stream>>>(x, wp, sums, hist_x, hist_d);
    codec_final<<<1, dim3(256), 0, stream>>>(sums, hist_x, hist_d, (float*)d_out);
}

// Round 2
// 3731.683 us; speedup vs baseline: 1.3193x; 1.3193x over previous
//
#include <hip/hip_runtime.h>
#include <cmath>

#define HH 512
#define WW 512
#define NIMG 12
#define RES (HH*WW)
#define NBINS 256

struct WPtrs {
    const float* wT[3]; const float* bT[3]; const float* wL[3];
    const float* w1[3]; const float* b1[3];
    const float* w2[3]; const float* b2[3];
    const float* w3[3]; const float* b3[3];
};

__global__ __launch_bounds__(256) void codec_main(
    const float* __restrict__ x, WPtrs wp,
    float* __restrict__ sums,            // [0]=sum x^2, [1]=sum delta^2
    unsigned* __restrict__ hist_x,       // [12][256]
    unsigned* __restrict__ hist_d)       // [12][256]
{
    __shared__ unsigned shx[NBINS], shd[NBINS];
    __shared__ float red[8];

    const int tid = threadIdx.x;
    shx[tid] = 0u; shd[tid] = 0u;
    __syncthreads();

    const int img = blockIdx.y;
    const int t = blockIdx.x * 256 + tid;     // pixel index within image
    const int i = t >> 9;                     // row
    const int j = t & (WW - 1);               // col
    const float* __restrict__ X = x + (size_t)img * RES;

    // ---- gather causal patch (zero padded) ----
    float pT[21], pL[3];
    #pragma unroll
    for (int r = 0; r < 3; ++r) {
        const int row = i - 3 + r;
        #pragma unroll
        for (int c = 0; c < 7; ++c) {
            const int col = j - 3 + c;
            pT[r*7 + c] = (row >= 0 && col >= 0 && col < WW) ? X[row*WW + col] : 0.0f;
        }
    }
    #pragma unroll
    for (int k = 0; k < 3; ++k) {
        const int col = j - 3 + k;
        pL[k] = (col >= 0) ? X[i*WW + col] : 0.0f;
    }
    const float xv = X[i*WW + j];

    // ---- three predictors; weights read via uniform (scalar) loads ----
    float pred[3];
    #pragma unroll 1
    for (int p = 0; p < 3; ++p) {
        const float* __restrict__ wT = wp.wT[p];
        const float* __restrict__ bT = wp.bT[p];
        const float* __restrict__ wL = wp.wL[p];
        const float* __restrict__ w1 = wp.w1[p];
        const float* __restrict__ b1 = wp.b1[p];
        const float* __restrict__ w2 = wp.w2[p];
        const float* __restrict__ b2 = wp.b2[p];
        const float* __restrict__ w3 = wp.w3[p];
        const float* __restrict__ b3 = wp.b3[p];

        float h0[32], h1[32];
        #pragma unroll
        for (int c = 0; c < 32; ++c) {
            float acc = bT[c];
            #pragma unroll
            for (int k = 0; k < 21; ++k) acc += wT[c*21 + k] * pT[k];
            #pragma unroll
            for (int k = 0; k < 3;  ++k) acc += wL[c*3 + k] * pL[k];
            h0[c] = acc >= 0.0f ? acc : 0.01f*acc;
        }
        #pragma unroll
        for (int co = 0; co < 32; ++co) {
            float acc = b1[co];
            #pragma unroll
            for (int ci = 0; ci < 32; ++ci) acc += w1[co*32 + ci] * h0[ci];
            h1[co] = acc >= 0.0f ? acc : 0.01f*acc;
        }
        #pragma unroll
        for (int co = 0; co < 32; ++co) {
            float acc = b2[co];
            #pragma unroll
            for (int ci = 0; ci < 32; ++ci) acc += w2[co*32 + ci] * h1[ci];
            h0[co] = acc >= 0.0f ? acc : 0.01f*acc;   // reuse h0 as h2
        }
        float acc = b3[0];
        #pragma unroll
        for (int ci = 0; ci < 32; ++ci) acc += w3[ci] * h0[ci];
        pred[p] = fminf(fmaxf(acc, -1.0f), 1.0f);
    }

    // ---- median-of-3 predictor + wrap-around residual ----
    const float a = pred[0], b = pred[1], c = pred[2];
    const float med = fmaxf(fminf(a, fmaxf(b, c)), fminf(b, c));
    const float delta = fmodf(xv - med + 1.0f, 2.0f) - 1.0f;

    // ---- histograms (histc semantics: out-of-range excluded) ----
    if (xv >= -1.0f && xv <= 1.0f) {
        int bin = (int)floorf((xv + 1.0f) * 128.0f);
        bin = bin < 0 ? 0 : (bin > 255 ? 255 : bin);
        atomicAdd(&shx[bin], 1u);
    }
    if (delta >= -1.0f && delta <= 1.0f) {
        int bin = (int)floorf((delta + 1.0f) * 128.0f);
        bin = bin < 0 ? 0 : (bin > 255 ? 255 : bin);
        atomicAdd(&shd[bin], 1u);
    }

    // ---- sum-of-squares reduction ----
    float sx = xv * xv, sd = delta * delta;
    #pragma unroll
    for (int off = 32; off > 0; off >>= 1) {
        sx += __shfl_down(sx, off);
        sd += __shfl_down(sd, off);
    }
    const int lane = tid & 63, wv = tid >> 6;
    if (lane == 0) { red[wv] = sx; red[4 + wv] = sd; }
    __syncthreads();
    if (tid == 0) {
        atomicAdd(&sums[0], red[0] + red[1] + red[2] + red[3]);
        atomicAdd(&sums[1], red[4] + red[5] + red[6] + red[7]);
    }
    if (shx[tid]) atomicAdd(&hist_x[img*NBINS + tid], shx[tid]);
    if (shd[tid]) atomicAdd(&hist_d[img*NBINS + tid], shd[tid]);
}

__global__ __launch_bounds__(256) void codec_final(
    const float* __restrict__ sums,
    const unsigned* __restrict__ hist_x,
    const unsigned* __restrict__ hist_d,
    float* __restrict__ out)
{
    __shared__ float red[16];
    const int tid = threadIdx.x;
    float ex = 0.0f, ed = 0.0f;
    const float inv_res = 1.0f / (float)RES;
    for (int k = tid; k < NIMG*NBINS; k += 256) {
        const unsigned hx = hist_x[k];
        const unsigned hd = hist_d[k];
        if (hx) { const float p = (float)hx * inv_res; ex -= p * log2f(p); }
        if (hd) { const float p = (float)hd * inv_res; ed -= p * log2f(p); }
    }
    #pragma unroll
    for (int off = 32; off > 0; off >>= 1) {
        ex += __shfl_down(ex, off);
        ed += __shfl_down(ed, off);
    }
    const int lane = tid & 63, wv = tid >> 6;
    if (lane == 0) { red[wv] = ex; red[8 + wv] = ed; }
    __syncthreads();
    if (tid == 0) {
        const float Ex = red[0] + red[1] + red[2] + red[3];
        const float Ed = red[8] + red[9] + red[10] + red[11];
        const float inv_n = 1.0f / (float)(NIMG * RES);
        out[0] = 255.0f * sqrtf(sums[1] * inv_n);   // loss1 (deltas)
        out[1] = 255.0f * sqrtf(sums[0] * inv_n);   // loss0 (x)
        out[2] = Ex / (8.0f * (float)NIMG);         // invCR0
        out[3] = Ed / (8.0f * (float)NIMG);         // invCR1
    }
}

extern "C" void kernel_launch(void* const* d_in, const int* in_sizes, int n_in,
                              void* d_out, int out_size, void* d_ws, size_t ws_size,
                              hipStream_t stream)
{
    const float* x = (const float*)d_in[0];
    WPtrs wp;
    for (int p = 0; p < 3; ++p) {
        const int b = 1 + 9*p;
        wp.wT[p] = (const float*)d_in[b+0];
        wp.bT[p] = (const float*)d_in[b+1];
        wp.wL[p] = (const float*)d_in[b+2];
        wp.w1[p] = (const float*)d_in[b+3];
        wp.b1[p] = (const float*)d_in[b+4];
        wp.w2[p] = (const float*)d_in[b+5];
        wp.b2[p] = (const float*)d_in[b+6];
        wp.w3[p] = (const float*)d_in[b+7];
        wp.b3[p] = (const float*)d_in[b+8];
    }

    float*    sums   = (float*)d_ws;
    unsigned* hist_x = (unsigned*)((char*)d_ws + 16);
    unsigned* hist_d = hist_x + NIMG*NBINS;
    const size_t zbytes = 16 + (size_t)2*NIMG*NBINS*sizeof(unsigned);
    hipMemsetAsync(d_ws, 0, zbytes, stream);

    dim3 grid(RES/256, NIMG);
    codec_main<<<grid, dim3(256), 0, stream>>>(x, wp, sums, hist_x, hist_d);
    codec_final<<<1, dim3(256), 0, stream>>>(sums, hist_x, hist_d, (float*)d_out);
}

// Round 3
// 981.215 us; speedup vs baseline: 5.0173x; 3.8031x over previous
//
#include <hip/hip_runtime.h>
#include <cmath>

#define HH 512
#define WW 512
#define NIMG 12
#define RES (HH*WW)
#define NBINS 256

// One predictor MLP on a causal patch; all weight pointers are kernel-level
// __restrict__ params so uniform loads lower to s_load (scalar cache).
__device__ __forceinline__ float predictor(
    const float pT[21], const float pL[3],
    const float* wT, const float* bT, const float* wL,
    const float* w1, const float* b1,
    const float* w2, const float* b2,
    const float* w3, const float* b3)
{
    float h0[32], h1[32];
    #pragma unroll
    for (int c = 0; c < 32; ++c) {
        float acc = bT[c];
        #pragma unroll
        for (int k = 0; k < 21; ++k) acc += wT[c*21 + k] * pT[k];
        #pragma unroll
        for (int k = 0; k < 3;  ++k) acc += wL[c*3 + k] * pL[k];
        h0[c] = fmaxf(acc, 0.01f*acc);          // leaky relu (slope<1)
    }
    #pragma unroll
    for (int co = 0; co < 32; ++co) {
        float acc = b1[co];
        #pragma unroll
        for (int ci = 0; ci < 32; ++ci) acc += w1[co*32 + ci] * h0[ci];
        h1[co] = fmaxf(acc, 0.01f*acc);
    }
    #pragma unroll
    for (int co = 0; co < 32; ++co) {
        float acc = b2[co];
        #pragma unroll
        for (int ci = 0; ci < 32; ++ci) acc += w2[co*32 + ci] * h1[ci];
        h0[co] = fmaxf(acc, 0.01f*acc);          // reuse as h2
    }
    float acc = b3[0];
    #pragma unroll
    for (int ci = 0; ci < 32; ++ci) acc += w3[ci] * h0[ci];
    return fminf(fmaxf(acc, -1.0f), 1.0f);
}

__global__ __launch_bounds__(256) void codec_main(
    const float* __restrict__ x,
    const float* __restrict__ a_wT, const float* __restrict__ a_bT, const float* __restrict__ a_wL,
    const float* __restrict__ a_w1, const float* __restrict__ a_b1,
    const float* __restrict__ a_w2, const float* __restrict__ a_b2,
    const float* __restrict__ a_w3, const float* __restrict__ a_b3,
    const float* __restrict__ b_wT, const float* __restrict__ b_bT, const float* __restrict__ b_wL,
    const float* __restrict__ b_w1, const float* __restrict__ b_b1,
    const float* __restrict__ b_w2, const float* __restrict__ b_b2,
    const float* __restrict__ b_w3, const float* __restrict__ b_b3,
    const float* __restrict__ c_wT, const float* __restrict__ c_bT, const float* __restrict__ c_wL,
    const float* __restrict__ c_w1, const float* __restrict__ c_b1,
    const float* __restrict__ c_w2, const float* __restrict__ c_b2,
    const float* __restrict__ c_w3, const float* __restrict__ c_b3,
    float* __restrict__ sums,            // [0]=sum x^2, [1]=sum delta^2
    unsigned* __restrict__ hist_x,       // [12][256]
    unsigned* __restrict__ hist_d)       // [12][256]
{
    __shared__ unsigned shx[NBINS], shd[NBINS];
    __shared__ float red[8];

    const int tid = threadIdx.x;
    shx[tid] = 0u; shd[tid] = 0u;
    __syncthreads();

    const int img = blockIdx.y;
    const int t = blockIdx.x * 256 + tid;     // pixel index within image
    const int i = t >> 9;                     // row
    const int j = t & (WW - 1);               // col
    const float* __restrict__ X = x + (size_t)img * RES;

    // ---- gather causal patch (zero padded) ----
    float pT[21], pL[3];
    #pragma unroll
    for (int r = 0; r < 3; ++r) {
        const int row = i - 3 + r;
        #pragma unroll
        for (int c = 0; c < 7; ++c) {
            const int col = j - 3 + c;
            pT[r*7 + c] = (row >= 0 && col >= 0 && col < WW) ? X[row*WW + col] : 0.0f;
        }
    }
    #pragma unroll
    for (int k = 0; k < 3; ++k) {
        const int col = j - 3 + k;
        pL[k] = (col >= 0) ? X[i*WW + col] : 0.0f;
    }
    const float xv = X[i*WW + j];

    // ---- three predictors (weights through scalar cache) ----
    const float pa = predictor(pT, pL, a_wT, a_bT, a_wL, a_w1, a_b1, a_w2, a_b2, a_w3, a_b3);
    const float pb = predictor(pT, pL, b_wT, b_bT, b_wL, b_w1, b_b1, b_w2, b_b2, b_w3, b_b3);
    const float pc = predictor(pT, pL, c_wT, c_bT, c_wL, c_w1, c_b1, c_w2, c_b2, c_w3, c_b3);

    // ---- median-of-3 predictor + wrap-around residual ----
    const float med = fmaxf(fminf(pa, fmaxf(pb, pc)), fminf(pb, pc));
    const float delta = fmodf(xv - med + 1.0f, 2.0f) - 1.0f;

    // ---- histograms (histc semantics: out-of-range excluded) ----
    if (xv >= -1.0f && xv <= 1.0f) {
        int bin = (int)floorf((xv + 1.0f) * 128.0f);
        bin = bin < 0 ? 0 : (bin > 255 ? 255 : bin);
        atomicAdd(&shx[bin], 1u);
    }
    if (delta >= -1.0f && delta <= 1.0f) {
        int bin = (int)floorf((delta + 1.0f) * 128.0f);
        bin = bin < 0 ? 0 : (bin > 255 ? 255 : bin);
        atomicAdd(&shd[bin], 1u);
    }

    // ---- sum-of-squares reduction ----
    float sx = xv * xv, sd = delta * delta;
    #pragma unroll
    for (int off = 32; off > 0; off >>= 1) {
        sx += __shfl_down(sx, off);
        sd += __shfl_down(sd, off);
    }
    const int lane = tid & 63, wv = tid >> 6;
    if (lane == 0) { red[wv] = sx; red[4 + wv] = sd; }
    __syncthreads();
    if (tid == 0) {
        atomicAdd(&sums[0], red[0] + red[1] + red[2] + red[3]);
        atomicAdd(&sums[1], red[4] + red[5] + red[6] + red[7]);
    }
    if (shx[tid]) atomicAdd(&hist_x[img*NBINS + tid], shx[tid]);
    if (shd[tid]) atomicAdd(&hist_d[img*NBINS + tid], shd[tid]);
}

__global__ __launch_bounds__(256) void codec_final(
    const float* __restrict__ sums,
    const unsigned* __restrict__ hist_x,
    const unsigned* __restrict__ hist_d,
    float* __restrict__ out)
{
    __shared__ float red[16];
    const int tid = threadIdx.x;
    float ex = 0.0f, ed = 0.0f;
    const float inv_res = 1.0f / (float)RES;
    for (int k = tid; k < NIMG*NBINS; k += 256) {
        const unsigned hx = hist_x[k];
        const unsigned hd = hist_d[k];
        if (hx) { const float p = (float)hx * inv_res; ex -= p * log2f(p); }
        if (hd) { const float p = (float)hd * inv_res; ed -= p * log2f(p); }
    }
    #pragma unroll
    for (int off = 32; off > 0; off >>= 1) {
        ex += __shfl_down(ex, off);
        ed += __shfl_down(ed, off);
    }
    const int lane = tid & 63, wv = tid >> 6;
    if (lane == 0) { red[wv] = ex; red[8 + wv] = ed; }
    __syncthreads();
    if (tid == 0) {
        const float Ex = red[0] + red[1] + red[2] + red[3];
        const float Ed = red[8] + red[9] + red[10] + red[11];
        const float inv_n = 1.0f / (float)(NIMG * RES);
        out[0] = 255.0f * sqrtf(sums[1] * inv_n);   // loss1 (deltas)
        out[1] = 255.0f * sqrtf(sums[0] * inv_n);   // loss0 (x)
        out[2] = Ex / (8.0f * (float)NIMG);         // invCR0
        out[3] = Ed / (8.0f * (float)NIMG);         // invCR1
    }
}

extern "C" void kernel_launch(void* const* d_in, const int* in_sizes, int n_in,
                              void* d_out, int out_size, void* d_ws, size_t ws_size,
                              hipStream_t stream)
{
    const float* x = (const float*)d_in[0];
    const float** w = (const float**)alloca(27 * sizeof(float*));
    for (int k = 0; k < 27; ++k) w[k] = (const float*)d_in[1 + k];

    float*    sums   = (float*)d_ws;
    unsigned* hist_x = (unsigned*)((char*)d_ws + 16);
    unsigned* hist_d = hist_x + NIMG*NBINS;
    const size_t zbytes = 16 + (size_t)2*NIMG*NBINS*sizeof(unsigned);
    hipMemsetAsync(d_ws, 0, zbytes, stream);

    dim3 grid(RES/256, NIMG);
    codec_main<<<grid, dim3(256), 0, stream>>>(
        x,
        w[0],  w[1],  w[2],  w[3],  w[4],  w[5],  w[6],  w[7],  w[8],
        w[9],  w[10], w[11], w[12], w[13], w[14], w[15], w[16], w[17],
        w[18], w[19], w[20], w[21], w[22], w[23], w[24], w[25], w[26],
        sums, hist_x, hist_d);
    codec_final<<<1, dim3(256), 0, stream>>>(sums, hist_x, hist_d, (float*)d_out);
}

// Round 4
// 648.481 us; speedup vs baseline: 7.5917x; 1.5131x over previous
//
#include <hip/hip_runtime.h>
#include <cmath>

#define HH 512
#define WW 512
#define NIMG 12
#define RES (HH*WW)
#define NBINS 256
#define PXB 1024            // pixels per block (4 waves)
#define PXW 256             // pixels per wave (16 n-tiles of 16)

typedef __attribute__((ext_vector_type(8))) short bf8;     // 8 bf16 (4 VGPR) MFMA A/B frag
typedef __attribute__((ext_vector_type(4))) short s16x4;   // 4 bf16 (8B)
typedef __attribute__((ext_vector_type(4))) float f32x4;   // MFMA C/D frag

__device__ __forceinline__ unsigned bf_rne(float x) {      // f32 -> bf16 bits, round-nearest-even
    unsigned u = __float_as_uint(x);
    return (u + 0x7fffu + ((u >> 16) & 1u)) >> 16;
}
__device__ __forceinline__ float lk(float a) { return fmaxf(a, 0.01f * a); }  // leaky relu

// unpack two packed-bf16 pairs into an f32x4 accumulator init (bias)
__device__ __forceinline__ f32x4 bias_init(unsigned pk0, unsigned pk1) {
    f32x4 c;
    c[0] = __uint_as_float(pk0 << 16);
    c[1] = __uint_as_float(pk0 & 0xffff0000u);
    c[2] = __uint_as_float(pk1 << 16);
    c[3] = __uint_as_float(pk1 & 0xffff0000u);
    return c;
}

#define MFMA(A, B, C) __builtin_amdgcn_mfma_f32_16x16x32_bf16((A), (B), (C), 0, 0, 0)

__global__ __launch_bounds__(256) void codec_main(
    const float* __restrict__ x,
    const float* __restrict__ a_wT, const float* __restrict__ a_bT, const float* __restrict__ a_wL,
    const float* __restrict__ a_w1, const float* __restrict__ a_b1,
    const float* __restrict__ a_w2, const float* __restrict__ a_b2,
    const float* __restrict__ a_w3, const float* __restrict__ a_b3,
    const float* __restrict__ b_wT, const float* __restrict__ b_bT, const float* __restrict__ b_wL,
    const float* __restrict__ b_w1, const float* __restrict__ b_b1,
    const float* __restrict__ b_w2, const float* __restrict__ b_b2,
    const float* __restrict__ b_w3, const float* __restrict__ b_b3,
    const float* __restrict__ c_wT, const float* __restrict__ c_bT, const float* __restrict__ c_wL,
    const float* __restrict__ c_w1, const float* __restrict__ c_b1,
    const float* __restrict__ c_w2, const float* __restrict__ c_b2,
    const float* __restrict__ c_w3, const float* __restrict__ c_b3,
    float* __restrict__ sums,
    unsigned* __restrict__ hist_x,
    unsigned* __restrict__ hist_d)
{
    __shared__ __align__(16) short rt[4][16*40];   // per-wave round-trip: 16 px rows x 40 shorts (80B, padded)
    __shared__ float predbuf[3][4][PXW];
    __shared__ unsigned shx[NBINS], shd[NBINS];
    __shared__ float red[8];

    const int tid  = threadIdx.x;
    const int lane = tid & 63;
    const int wv   = tid >> 6;
    const int q    = lane >> 4;     // quad group: supplies k = 8q+j (A/B), rows 4q+r (C/D)
    const int m16  = lane & 15;     // m (A) / n=pixel (B,C/D)

    shx[tid] = 0u; shd[tid] = 0u;
    __syncthreads();

    const float* wTp[3] = {a_wT, b_wT, c_wT};
    const float* bTp[3] = {a_bT, b_bT, c_bT};
    const float* wLp[3] = {a_wL, b_wL, c_wL};
    const float* w1p[3] = {a_w1, b_w1, c_w1};
    const float* b1p[3] = {a_b1, b_b1, c_b1};
    const float* w2p[3] = {a_w2, b_w2, c_w2};
    const float* b2p[3] = {a_b2, b_b2, c_b2};
    const float* w3p[3] = {a_w3, b_w3, c_w3};
    const float* b3p[3] = {a_b3, b_b3, c_b3};

    // ---- per-wave one-time: weights -> MFMA A-frags (A[m=m16][k=8q+j]) ----
    bf8 wA0[3][2], wA1[3][2], wA2[3][2];
    unsigned bp1[3][2][2], bp2[3][2][2];
    float w3v[3][8];
    float b3v[3];
    #pragma unroll
    for (int p = 0; p < 3; ++p) {
        #pragma unroll
        for (int mt = 0; mt < 2; ++mt) {
            const int ch = 16*mt + m16;
            // layer0: K = 21 top + 3 left + bias row (k=24) + zero pad
            bf8 f0;
            #pragma unroll
            for (int j = 0; j < 8; ++j) {
                const int k = 8*q + j;
                float v = 0.0f;
                if (k < 21)       v = wTp[p][ch*21 + k];
                else if (k < 24)  v = wLp[p][ch*3 + (k - 21)];
                else if (k == 24) v = bTp[p][ch];
                f0[j] = (short)bf_rne(v);
            }
            wA0[p][mt] = f0;
            // layers 1,2: W[ch][ci], k=ci
            {
                const f32x4 lo = *(const f32x4*)&w1p[p][ch*32 + 8*q];
                const f32x4 hi = *(const f32x4*)&w1p[p][ch*32 + 8*q + 4];
                bf8 g;
                #pragma unroll
                for (int j = 0; j < 4; ++j) { g[j] = (short)bf_rne(lo[j]); g[4+j] = (short)bf_rne(hi[j]); }
                wA1[p][mt] = g;
            }
            {
                const f32x4 lo = *(const f32x4*)&w2p[p][ch*32 + 8*q];
                const f32x4 hi = *(const f32x4*)&w2p[p][ch*32 + 8*q + 4];
                bf8 g;
                #pragma unroll
                for (int j = 0; j < 4; ++j) { g[j] = (short)bf_rne(lo[j]); g[4+j] = (short)bf_rne(hi[j]); }
                wA2[p][mt] = g;
            }
            // biases in C-layout (row = 16mt+4q+r), packed bf16
            {
                const f32x4 bv = *(const f32x4*)&b1p[p][16*mt + 4*q];
                bp1[p][mt][0] = (bf_rne(bv[1]) << 16) | bf_rne(bv[0]);
                bp1[p][mt][1] = (bf_rne(bv[3]) << 16) | bf_rne(bv[2]);
            }
            {
                const f32x4 bv = *(const f32x4*)&b2p[p][16*mt + 4*q];
                bp2[p][mt][0] = (bf_rne(bv[1]) << 16) | bf_rne(bv[0]);
                bp2[p][mt][1] = (bf_rne(bv[3]) << 16) | bf_rne(bv[2]);
            }
            // layer3 weights in C-layout, f32
            {
                const f32x4 wv3 = *(const f32x4*)&w3p[p][16*mt + 4*q];
                #pragma unroll
                for (int r = 0; r < 4; ++r) w3v[p][mt*4 + r] = wv3[r];
            }
        }
        b3v[p] = b3p[p][0];
    }

    const int img = blockIdx.y;
    const float* __restrict__ X = x + (size_t)img * RES;
    const int wbase = blockIdx.x * PXB + wv * PXW;
    short* rtw = &rt[wv][0];

    // ---- main loop: 16 n-tiles of 16 pixels ----
    #pragma unroll 1
    for (int t = 0; t < 16; ++t) {
        const int px = wbase + t*16 + m16;
        const int i  = px >> 9;
        const int jc = px & (WW - 1);

        // patch B-frag: B[k=8q+j][n=px]
        bf8 pf;
        #pragma unroll
        for (int j = 0; j < 8; ++j) {
            const int k = 8*q + j;
            float v = 0.0f;
            if (k < 21) {
                const int rr = i - 3 + k/7;
                const int cc = jc - 3 + k%7;
                if (rr >= 0 && cc >= 0 && cc < WW) v = X[rr*WW + cc];
            } else if (k < 24) {
                const int cc = jc - 3 + (k - 21);
                if (cc >= 0) v = X[i*WW + cc];
            } else if (k == 24) {
                v = 1.0f;   // bias row for layer0
            }
            pf[j] = (short)bf_rne(v);
        }

        float pr[3];
        #pragma unroll
        for (int p = 0; p < 3; ++p) {
            const f32x4 z = {0.f, 0.f, 0.f, 0.f};
            f32x4 a0 = MFMA(wA0[p][0], pf, z);
            f32x4 a1 = MFMA(wA0[p][1], pf, z);
            // leaky + bf16 + LDS round trip (C-layout -> B-layout)
            {
                s16x4 v0, v1;
                #pragma unroll
                for (int r = 0; r < 4; ++r) { v0[r] = (short)bf_rne(lk(a0[r])); v1[r] = (short)bf_rne(lk(a1[r])); }
                *(s16x4*)&rtw[m16*40 +      q*4] = v0;
                *(s16x4*)&rtw[m16*40 + 16 + q*4] = v1;
            }
            bf8 h = *(const bf8*)&rtw[m16*40 + q*8];
            a0 = MFMA(wA1[p][0], h, bias_init(bp1[p][0][0], bp1[p][0][1]));
            a1 = MFMA(wA1[p][1], h, bias_init(bp1[p][1][0], bp1[p][1][1]));
            {
                s16x4 v0, v1;
                #pragma unroll
                for (int r = 0; r < 4; ++r) { v0[r] = (short)bf_rne(lk(a0[r])); v1[r] = (short)bf_rne(lk(a1[r])); }
                *(s16x4*)&rtw[m16*40 +      q*4] = v0;
                *(s16x4*)&rtw[m16*40 + 16 + q*4] = v1;
            }
            h = *(const bf8*)&rtw[m16*40 + q*8];
            a0 = MFMA(wA2[p][0], h, bias_init(bp2[p][0][0], bp2[p][0][1]));
            a1 = MFMA(wA2[p][1], h, bias_init(bp2[p][1][0], bp2[p][1][1]));
            // layer3 dot on f32 regs + cross-quad reduce
            float part = 0.0f;
            #pragma unroll
            for (int r = 0; r < 4; ++r) part += w3v[p][r]     * lk(a0[r]);
            #pragma unroll
            for (int r = 0; r < 4; ++r) part += w3v[p][4 + r] * lk(a1[r]);
            part += __shfl_xor(part, 16);
            part += __shfl_xor(part, 32);
            pr[p] = fminf(fmaxf(part + b3v[p], -1.0f), 1.0f);
        }
        if (q == 0) {
            predbuf[0][wv][t*16 + m16] = pr[0];
            predbuf[1][wv][t*16 + m16] = pr[1];
            predbuf[2][wv][t*16 + m16] = pr[2];
        }
    }

    // ---- stats: median, residual, histograms, sums ----
    float sx = 0.0f, sd = 0.0f;
    #pragma unroll 1
    for (int it = 0; it < 4; ++it) {
        const int pl = it*64 + lane;
        const int px = wbase + pl;
        const float xv = X[px];
        const float pa = predbuf[0][wv][pl];
        const float pb = predbuf[1][wv][pl];
        const float pc = predbuf[2][wv][pl];
        const float med = fmaxf(fminf(pa, fmaxf(pb, pc)), fminf(pb, pc));
        const float delta = fmodf(xv - med + 1.0f, 2.0f) - 1.0f;
        if (xv >= -1.0f && xv <= 1.0f) {
            int bin = (int)floorf((xv + 1.0f) * 128.0f);
            bin = bin < 0 ? 0 : (bin > 255 ? 255 : bin);
            atomicAdd(&shx[bin], 1u);
        }
        if (delta >= -1.0f && delta <= 1.0f) {
            int bin = (int)floorf((delta + 1.0f) * 128.0f);
            bin = bin < 0 ? 0 : (bin > 255 ? 255 : bin);
            atomicAdd(&shd[bin], 1u);
        }
        sx += xv*xv; sd += delta*delta;
    }
    #pragma unroll
    for (int off = 32; off > 0; off >>= 1) {
        sx += __shfl_down(sx, off);
        sd += __shfl_down(sd, off);
    }
    if (lane == 0) { red[wv] = sx; red[4 + wv] = sd; }
    __syncthreads();
    if (tid == 0) {
        atomicAdd(&sums[0], red[0] + red[1] + red[2] + red[3]);
        atomicAdd(&sums[1], red[4] + red[5] + red[6] + red[7]);
    }
    if (shx[tid]) atomicAdd(&hist_x[img*NBINS + tid], shx[tid]);
    if (shd[tid]) atomicAdd(&hist_d[img*NBINS + tid], shd[tid]);
}

__global__ __launch_bounds__(256) void codec_final(
    const float* __restrict__ sums,
    const unsigned* __restrict__ hist_x,
    const unsigned* __restrict__ hist_d,
    float* __restrict__ out)
{
    __shared__ float red[16];
    const int tid = threadIdx.x;
    float ex = 0.0f, ed = 0.0f;
    const float inv_res = 1.0f / (float)RES;
    for (int k = tid; k < NIMG*NBINS; k += 256) {
        const unsigned hx = hist_x[k];
        const unsigned hd = hist_d[k];
        if (hx) { const float p = (float)hx * inv_res; ex -= p * log2f(p); }
        if (hd) { const float p = (float)hd * inv_res; ed -= p * log2f(p); }
    }
    #pragma unroll
    for (int off = 32; off > 0; off >>= 1) {
        ex += __shfl_down(ex, off);
        ed += __shfl_down(ed, off);
    }
    const int lane = tid & 63, wv = tid >> 6;
    if (lane == 0) { red[wv] = ex; red[8 + wv] = ed; }
    __syncthreads();
    if (tid == 0) {
        const float Ex = red[0] + red[1] + red[2] + red[3];
        const float Ed = red[8] + red[9] + red[10] + red[11];
        const float inv_n = 1.0f / (float)(NIMG * RES);
        out[0] = 255.0f * sqrtf(sums[1] * inv_n);   // loss1 (deltas)
        out[1] = 255.0f * sqrtf(sums[0] * inv_n);   // loss0 (x)
        out[2] = Ex / (8.0f * (float)NIMG);         // invCR0
        out[3] = Ed / (8.0f * (float)NIMG);         // invCR1
    }
}

extern "C" void kernel_launch(void* const* d_in, const int* in_sizes, int n_in,
                              void* d_out, int out_size, void* d_ws, size_t ws_size,
                              hipStream_t stream)
{
    const float* x = (const float*)d_in[0];
    const float* w[27];
    for (int k = 0; k < 27; ++k) w[k] = (const float*)d_in[1 + k];

    float*    sums   = (float*)d_ws;
    unsigned* hist_x = (unsigned*)((char*)d_ws + 16);
    unsigned* hist_d = hist_x + NIMG*NBINS;
    const size_t zbytes = 16 + (size_t)2*NIMG*NBINS*sizeof(unsigned);
    hipMemsetAsync(d_ws, 0, zbytes, stream);

    dim3 grid(RES/PXB, NIMG);
    codec_main<<<grid, dim3(256), 0, stream>>>(
        x,
        w[0],  w[1],  w[2],  w[3],  w[4],  w[5],  w[6],  w[7],  w[8],
        w[9],  w[10], w[11], w[12], w[13], w[14], w[15], w[16], w[17],
        w[18], w[19], w[20], w[21], w[22], w[23], w[24], w[25], w[26],
        sums, hist_x, hist_d);
    codec_final<<<1, dim3(256), 0, stream>>>(sums, hist_x, hist_d, (float*)d_out);
}

// Round 5
// 597.862 us; speedup vs baseline: 8.2344x; 1.0847x over previous
//
#include <hip/hip_runtime.h>
#include <hip/hip_bf16.h>
#include <cmath>

#define HH 512
#define WW 512
#define NIMG 12
#define RES (HH*WW)
#define NBINS 256
#define PXB 1024            // pixels per block (4 waves)
#define PXW 256             // pixels per wave (16 n-tiles of 16)

typedef __attribute__((ext_vector_type(8))) short bf8;     // 8 bf16 (4 VGPR) MFMA A/B frag
typedef __attribute__((ext_vector_type(4))) float f32x4;   // MFMA C/D frag

__device__ __forceinline__ unsigned bf_rne(float x) {      // f32 -> bf16 bits (setup path)
    unsigned u = __float_as_uint(x);
    return (u + 0x7fffu + ((u >> 16) & 1u)) >> 16;
}
__device__ __forceinline__ float lk(float a) { return fmaxf(a, 0.01f * a); }  // leaky relu

__device__ __forceinline__ unsigned pk2(float a, float b) { // packed f32x2 -> bf16x2 (hot path)
    float2 t; t.x = a; t.y = b;
    union { __hip_bfloat162 h; unsigned u; } c;
    c.h = __float22bfloat162_rn(t);
    return c.u;
}

union bf8u { bf8 f; unsigned u[4]; };

// C/D frag pair -> next layer's B frag: frag[j] = j<4 ? a0[j] : a1[j-4]
// (valid because producing layer's rows are sigma-permuted; see sigma below)
__device__ __forceinline__ bf8 actfrag(const f32x4 a0, const f32x4 a1) {
    bf8u r;
    r.u[0] = pk2(lk(a0[0]), lk(a0[1]));
    r.u[1] = pk2(lk(a0[2]), lk(a0[3]));
    r.u[2] = pk2(lk(a1[0]), lk(a1[1]));
    r.u[3] = pk2(lk(a1[2]), lk(a1[3]));
    return r.f;
}

// unpack two packed-bf16 pairs into an f32x4 accumulator init (bias)
__device__ __forceinline__ f32x4 bias_init(unsigned pk0, unsigned pk1) {
    f32x4 c;
    c[0] = __uint_as_float(pk0 << 16);
    c[1] = __uint_as_float(pk0 & 0xffff0000u);
    c[2] = __uint_as_float(pk1 << 16);
    c[3] = __uint_as_float(pk1 & 0xffff0000u);
    return c;
}

#define MFMA(A, B, C) __builtin_amdgcn_mfma_f32_16x16x32_bf16((A), (B), (C), 0, 0, 0)

__global__ __launch_bounds__(256) void codec_main(
    const float* __restrict__ x,
    const float* __restrict__ a_wT, const float* __restrict__ a_bT, const float* __restrict__ a_wL,
    const float* __restrict__ a_w1, const float* __restrict__ a_b1,
    const float* __restrict__ a_w2, const float* __restrict__ a_b2,
    const float* __restrict__ a_w3, const float* __restrict__ a_b3,
    const float* __restrict__ b_wT, const float* __restrict__ b_bT, const float* __restrict__ b_wL,
    const float* __restrict__ b_w1, const float* __restrict__ b_b1,
    const float* __restrict__ b_w2, const float* __restrict__ b_b2,
    const float* __restrict__ b_w3, const float* __restrict__ b_b3,
    const float* __restrict__ c_wT, const float* __restrict__ c_bT, const float* __restrict__ c_wL,
    const float* __restrict__ c_w1, const float* __restrict__ c_b1,
    const float* __restrict__ c_w2, const float* __restrict__ c_b2,
    const float* __restrict__ c_w3, const float* __restrict__ c_b3,
    float* __restrict__ sums,
    unsigned* __restrict__ hist_x,
    unsigned* __restrict__ hist_d)
{
    __shared__ float predbuf[3][4][PXW];
    __shared__ unsigned shx[NBINS], shd[NBINS];
    __shared__ float red[8];

    const int tid  = threadIdx.x;
    const int lane = tid & 63;
    const int wv   = tid >> 6;
    const int q    = lane >> 4;     // quad group: k = 8q+j (A/B), rows 4q+r (C/D)
    const int m16  = lane & 15;     // m (A) / n=pixel (B, C/D)

    shx[tid] = 0u; shd[tid] = 0u;
    __syncthreads();

    const float* wTp[3] = {a_wT, b_wT, c_wT};
    const float* bTp[3] = {a_bT, b_bT, c_bT};
    const float* wLp[3] = {a_wL, b_wL, c_wL};
    const float* w1p[3] = {a_w1, b_w1, c_w1};
    const float* b1p[3] = {a_b1, b_b1, c_b1};
    const float* w2p[3] = {a_w2, b_w2, c_w2};
    const float* b2p[3] = {a_b2, b_b2, c_b2};
    const float* w3p[3] = {a_w3, b_w3, c_w3};
    const float* b3p[3] = {a_b3, b_b3, c_b3};

    // ---- one-time: weights -> MFMA A-frags, rows permuted by sigma ----
    // sigma(16*mt + m16) = 8*(m16>>2) + 4*mt + (m16&3): the channel this
    // lane's computed row m=16mt+m16 must hold so that the C/D frag IS the
    // next layer's B frag. Consuming layers then use natural column order.
    bf8 wA0[3][2], wA1[3][2], wA2[3][2];
    unsigned bp1[3][2][2], bp2[3][2][2];
    float w3v[3][8];
    float b3v[3];
    #pragma unroll
    for (int p = 0; p < 3; ++p) {
        #pragma unroll
        for (int mt = 0; mt < 2; ++mt) {
            const int ch = ((m16 >> 2) << 3) + (mt << 2) + (m16 & 3);   // sigma(16mt+m16)
            // layer0: K = 21 top + 3 left + bias row (k=24) + zero pad
            bf8 f0;
            #pragma unroll
            for (int j = 0; j < 8; ++j) {
                const int k = 8*q + j;
                float v = 0.0f;
                if (k < 21)       v = wTp[p][ch*21 + k];
                else if (k < 24)  v = wLp[p][ch*3 + (k - 21)];
                else if (k == 24) v = bTp[p][ch];
                f0[j] = (short)bf_rne(v);
            }
            wA0[p][mt] = f0;
            // layers 1,2: rows sigma-permuted, columns natural
            {
                const f32x4 lo = *(const f32x4*)&w1p[p][ch*32 + 8*q];
                const f32x4 hi = *(const f32x4*)&w1p[p][ch*32 + 8*q + 4];
                bf8 g;
                #pragma unroll
                for (int j = 0; j < 4; ++j) { g[j] = (short)bf_rne(lo[j]); g[4+j] = (short)bf_rne(hi[j]); }
                wA1[p][mt] = g;
            }
            {
                const f32x4 lo = *(const f32x4*)&w2p[p][ch*32 + 8*q];
                const f32x4 hi = *(const f32x4*)&w2p[p][ch*32 + 8*q + 4];
                bf8 g;
                #pragma unroll
                for (int j = 0; j < 4; ++j) { g[j] = (short)bf_rne(lo[j]); g[4+j] = (short)bf_rne(hi[j]); }
                wA2[p][mt] = g;
            }
            // biases at computed row 16mt+4q+r -> logical sigma(...) = 8q+4mt+r
            {
                const f32x4 bv = *(const f32x4*)&b1p[p][8*q + 4*mt];
                bp1[p][mt][0] = (bf_rne(bv[1]) << 16) | bf_rne(bv[0]);
                bp1[p][mt][1] = (bf_rne(bv[3]) << 16) | bf_rne(bv[2]);
            }
            {
                const f32x4 bv = *(const f32x4*)&b2p[p][8*q + 4*mt];
                bp2[p][mt][0] = (bf_rne(bv[1]) << 16) | bf_rne(bv[0]);
                bp2[p][mt][1] = (bf_rne(bv[3]) << 16) | bf_rne(bv[2]);
            }
            // layer3 weights in C-layout: w3[sigma(16mt+4q+r)] = w3[8q+4mt+r]
            {
                const f32x4 wv3 = *(const f32x4*)&w3p[p][8*q + 4*mt];
                #pragma unroll
                for (int r = 0; r < 4; ++r) w3v[p][mt*4 + r] = wv3[r];
            }
        }
        b3v[p] = b3p[p][0];
    }

    const int img = blockIdx.y;
    const float* __restrict__ X = x + (size_t)img * RES;
    const int wbase = blockIdx.x * PXB + wv * PXW;

    // ---- main loop: 16 n-tiles of 16 pixels, no LDS in the MLP chain ----
    #pragma unroll 1
    for (int t = 0; t < 16; ++t) {
        const int px = wbase + t*16 + m16;
        const int i  = px >> 9;
        const int jc = px & (WW - 1);

        // patch B-frag: B[k=8q+j][n=px]
        bf8 pf;
        #pragma unroll
        for (int j = 0; j < 8; ++j) {
            const int k = 8*q + j;
            float v = 0.0f;
            if (k < 21) {
                const int rr = i - 3 + k/7;
                const int cc = jc - 3 + k%7;
                if (rr >= 0 && cc >= 0 && cc < WW) v = X[rr*WW + cc];
            } else if (k < 24) {
                const int cc = jc - 3 + (k - 21);
                if (cc >= 0) v = X[i*WW + cc];
            } else if (k == 24) {
                v = 1.0f;   // bias row for layer0
            }
            pf[j] = (short)bf_rne(v);
        }

        float pr[3];
        #pragma unroll
        for (int p = 0; p < 3; ++p) {
            const f32x4 z = {0.f, 0.f, 0.f, 0.f};
            f32x4 a0 = MFMA(wA0[p][0], pf, z);
            f32x4 a1 = MFMA(wA0[p][1], pf, z);
            bf8 h = actfrag(a0, a1);                      // C->B for free (sigma)
            a0 = MFMA(wA1[p][0], h, bias_init(bp1[p][0][0], bp1[p][0][1]));
            a1 = MFMA(wA1[p][1], h, bias_init(bp1[p][1][0], bp1[p][1][1]));
            h = actfrag(a0, a1);
            a0 = MFMA(wA2[p][0], h, bias_init(bp2[p][0][0], bp2[p][0][1]));
            a1 = MFMA(wA2[p][1], h, bias_init(bp2[p][1][0], bp2[p][1][1]));
            // layer3 dot on f32 regs + cross-quad reduce
            float part = 0.0f;
            #pragma unroll
            for (int r = 0; r < 4; ++r) part += w3v[p][r]     * lk(a0[r]);
            #pragma unroll
            for (int r = 0; r < 4; ++r) part += w3v[p][4 + r] * lk(a1[r]);
            part += __shfl_xor(part, 16);
            part += __shfl_xor(part, 32);
            pr[p] = fminf(fmaxf(part + b3v[p], -1.0f), 1.0f);
        }
        if (q == 0) {
            predbuf[0][wv][t*16 + m16] = pr[0];
            predbuf[1][wv][t*16 + m16] = pr[1];
            predbuf[2][wv][t*16 + m16] = pr[2];
        }
    }

    // ---- stats: median, residual, histograms, sums ----
    float sx = 0.0f, sd = 0.0f;
    #pragma unroll 1
    for (int it = 0; it < 4; ++it) {
        const int pl = it*64 + lane;
        const int px = wbase + pl;
        const float xv = X[px];
        const float pa = predbuf[0][wv][pl];
        const float pb = predbuf[1][wv][pl];
        const float pc = predbuf[2][wv][pl];
        const float med = fmaxf(fminf(pa, fmaxf(pb, pc)), fminf(pb, pc));
        const float delta = fmodf(xv - med + 1.0f, 2.0f) - 1.0f;
        if (xv >= -1.0f && xv <= 1.0f) {
            int bin = (int)floorf((xv + 1.0f) * 128.0f);
            bin = bin < 0 ? 0 : (bin > 255 ? 255 : bin);
            atomicAdd(&shx[bin], 1u);
        }
        if (delta >= -1.0f && delta <= 1.0f) {
            int bin = (int)floorf((delta + 1.0f) * 128.0f);
            bin = bin < 0 ? 0 : (bin > 255 ? 255 : bin);
            atomicAdd(&shd[bin], 1u);
        }
        sx += xv*xv; sd += delta*delta;
    }
    #pragma unroll
    for (int off = 32; off > 0; off >>= 1) {
        sx += __shfl_down(sx, off);
        sd += __shfl_down(sd, off);
    }
    if (lane == 0) { red[wv] = sx; red[4 + wv] = sd; }
    __syncthreads();
    if (tid == 0) {
        atomicAdd(&sums[0], red[0] + red[1] + red[2] + red[3]);
        atomicAdd(&sums[1], red[4] + red[5] + red[6] + red[7]);
    }
    if (shx[tid]) atomicAdd(&hist_x[img*NBINS + tid], shx[tid]);
    if (shd[tid]) atomicAdd(&hist_d[img*NBINS + tid], shd[tid]);
}

__global__ __launch_bounds__(256) void codec_final(
    const float* __restrict__ sums,
    const unsigned* __restrict__ hist_x,
    const unsigned* __restrict__ hist_d,
    float* __restrict__ out)
{
    __shared__ float red[16];
    const int tid = threadIdx.x;
    float ex = 0.0f, ed = 0.0f;
    const float inv_res = 1.0f / (float)RES;
    for (int k = tid; k < NIMG*NBINS; k += 256) {
        const unsigned hx = hist_x[k];
        const unsigned hd = hist_d[k];
        if (hx) { const float p = (float)hx * inv_res; ex -= p * log2f(p); }
        if (hd) { const float p = (float)hd * inv_res; ed -= p * log2f(p); }
    }
    #pragma unroll
    for (int off = 32; off > 0; off >>= 1) {
        ex += __shfl_down(ex, off);
        ed += __shfl_down(ed, off);
    }
    const int lane = tid & 63, wv = tid >> 6;
    if (lane == 0) { red[wv] = ex; red[8 + wv] = ed; }
    __syncthreads();
    if (tid == 0) {
        const float Ex = red[0] + red[1] + red[2] + red[3];
        const float Ed = red[8] + red[9] + red[10] + red[11];
        const float inv_n = 1.0f / (float)(NIMG * RES);
        out[0] = 255.0f * sqrtf(sums[1] * inv_n);   // loss1 (deltas)
        out[1] = 255.0f * sqrtf(sums[0] * inv_n);   // loss0 (x)
        out[2] = Ex / (8.0f * (float)NIMG);         // invCR0
        out[3] = Ed / (8.0f * (float)NIMG);         // invCR1
    }
}

extern "C" void kernel_launch(void* const* d_in, const int* in_sizes, int n_in,
                              void* d_out, int out_size, void* d_ws, size_t ws_size,
                              hipStream_t stream)
{
    const float* x = (const float*)d_in[0];
    const float* w[27];
    for (int k = 0; k < 27; ++k) w[k] = (const float*)d_in[1 + k];

    float*    sums   = (float*)d_ws;
    unsigned* hist_x = (unsigned*)((char*)d_ws + 16);
    unsigned* hist_d = hist_x + NIMG*NBINS;
    const size_t zbytes = 16 + (size_t)2*NIMG*NBINS*sizeof(unsigned);
    hipMemsetAsync(d_ws, 0, zbytes, stream);

    dim3 grid(RES/PXB, NIMG);
    codec_main<<<grid, dim3(256), 0, stream>>>(
        x,
        w[0],  w[1],  w[2],  w[3],  w[4],  w[5],  w[6],  w[7],  w[8],
        w[9],  w[10], w[11], w[12], w[13], w[14], w[15], w[16], w[17],
        w[18], w[19], w[20], w[21], w[22], w[23], w[24], w[25], w[26],
        sums, hist_x, hist_d);
    codec_final<<<1, dim3(256), 0, stream>>>(sums, hist_x, hist_d, (float*)d_out);
}

// Round 6
// 479.754 us; speedup vs baseline: 10.2616x; 1.2462x over previous
//
#include <hip/hip_runtime.h>
#include <hip/hip_bf16.h>
#include <cmath>

#define HH 512
#define WW 512
#define NIMG 12
#define RES (HH*WW)
#define NBINS 256
#define PXB 1024            // pixels per block (4 waves)
#define PXW 256             // pixels per wave = half an image row

typedef __attribute__((ext_vector_type(8))) short bf8;     // 8 bf16 (4 VGPR) MFMA A/B frag
typedef __attribute__((ext_vector_type(4))) float f32x4;   // MFMA C/D frag

__device__ __forceinline__ unsigned bf_rne(float x) {      // f32 -> bf16 bits (setup/edge path)
    unsigned u = __float_as_uint(x);
    return (u + 0x7fffu + ((u >> 16) & 1u)) >> 16;
}
__device__ __forceinline__ float lk(float a) { return fmaxf(a, 0.01f * a); }  // leaky relu

__device__ __forceinline__ unsigned pk2(float a, float b) { // packed f32x2 -> bf16x2
    float2 t; t.x = a; t.y = b;
    union { __hip_bfloat162 h; unsigned u; } c;
    c.h = __float22bfloat162_rn(t);
    return c.u;
}

union bf8u { bf8 f; unsigned u[4]; };

// C/D frag pair -> next layer's B frag (valid due to sigma-permuted weight rows)
__device__ __forceinline__ bf8 actfrag(const f32x4 a0, const f32x4 a1) {
    bf8u r;
    r.u[0] = pk2(lk(a0[0]), lk(a0[1]));
    r.u[1] = pk2(lk(a0[2]), lk(a0[3]));
    r.u[2] = pk2(lk(a1[0]), lk(a1[1]));
    r.u[3] = pk2(lk(a1[2]), lk(a1[3]));
    return r.f;
}

__device__ __forceinline__ f32x4 bias_init(unsigned pk0, unsigned pk1) {
    f32x4 c;
    c[0] = __uint_as_float(pk0 << 16);
    c[1] = __uint_as_float(pk0 & 0xffff0000u);
    c[2] = __uint_as_float(pk1 << 16);
    c[3] = __uint_as_float(pk1 & 0xffff0000u);
    return c;
}

// edge-tile patch builder with full bounds checks (rare path)
__device__ __forceinline__ bf8 slow_build(const float* __restrict__ X,
                                          int i, int jb, int m16, int q)
{
    const int jc = jb + m16;
    bf8 pf;
    #pragma unroll
    for (int j = 0; j < 8; ++j) {
        const int k = 8*q + j;
        float v = 0.0f;
        if (k < 21) {
            const int rr = i - 3 + k/7;
            const int cc = jc - 3 + k%7;
            if (rr >= 0 && cc >= 0 && cc < WW) v = X[rr*WW + cc];
        } else if (k < 24) {
            const int cc = jc - 3 + (k - 21);
            if (cc >= 0) v = X[i*WW + cc];
        } else if (k == 24) {
            v = 1.0f;
        }
        pf[j] = (short)bf_rne(v);
    }
    return pf;
}

#define MFMA(A, B, C) __builtin_amdgcn_mfma_f32_16x16x32_bf16((A), (B), (C), 0, 0, 0)

__global__ __launch_bounds__(256) void codec_main(
    const float* __restrict__ x,
    const float* __restrict__ a_wT, const float* __restrict__ a_bT, const float* __restrict__ a_wL,
    const float* __restrict__ a_w1, const float* __restrict__ a_b1,
    const float* __restrict__ a_w2, const float* __restrict__ a_b2,
    const float* __restrict__ a_w3, const float* __restrict__ a_b3,
    const float* __restrict__ b_wT, const float* __restrict__ b_bT, const float* __restrict__ b_wL,
    const float* __restrict__ b_w1, const float* __restrict__ b_b1,
    const float* __restrict__ b_w2, const float* __restrict__ b_b2,
    const float* __restrict__ b_w3, const float* __restrict__ b_b3,
    const float* __restrict__ c_wT, const float* __restrict__ c_bT, const float* __restrict__ c_wL,
    const float* __restrict__ c_w1, const float* __restrict__ c_b1,
    const float* __restrict__ c_w2, const float* __restrict__ c_b2,
    const float* __restrict__ c_w3, const float* __restrict__ c_b3,
    float* __restrict__ sums,
    unsigned* __restrict__ hist_x,
    unsigned* __restrict__ hist_d)
{
    __shared__ unsigned shx[NBINS], shd[NBINS];
    __shared__ float red[8];

    const int tid  = threadIdx.x;
    const int lane = tid & 63;
    const int wv   = tid >> 6;
    const int q    = lane >> 4;     // quad group: k = 8q+j (A/B), rows 4q+r (C/D)
    const int m16  = lane & 15;     // m (A) / n=pixel (B, C/D)

    shx[tid] = 0u; shd[tid] = 0u;
    __syncthreads();

    const float* wTp[3] = {a_wT, b_wT, c_wT};
    const float* bTp[3] = {a_bT, b_bT, c_bT};
    const float* wLp[3] = {a_wL, b_wL, c_wL};
    const float* w1p[3] = {a_w1, b_w1, c_w1};
    const float* b1p[3] = {a_b1, b_b1, c_b1};
    const float* w2p[3] = {a_w2, b_w2, c_w2};
    const float* b2p[3] = {a_b2, b_b2, c_b2};
    const float* w3p[3] = {a_w3, b_w3, c_w3};
    const float* b3p[3] = {a_b3, b_b3, c_b3};

    // ---- one-time: weights -> MFMA A-frags, rows permuted by sigma ----
    bf8 wA0[3][2], wA1[3][2], wA2[3][2];
    unsigned bp1[3][2][2], bp2[3][2][2];
    float w3v[3][8];
    float b3v[3];
    #pragma unroll
    for (int p = 0; p < 3; ++p) {
        #pragma unroll
        for (int mt = 0; mt < 2; ++mt) {
            const int ch = ((m16 >> 2) << 3) + (mt << 2) + (m16 & 3);   // sigma(16mt+m16)
            bf8 f0;
            #pragma unroll
            for (int j = 0; j < 8; ++j) {
                const int k = 8*q + j;
                float v = 0.0f;
                if (k < 21)       v = wTp[p][ch*21 + k];
                else if (k < 24)  v = wLp[p][ch*3 + (k - 21)];
                else if (k == 24) v = bTp[p][ch];
                f0[j] = (short)bf_rne(v);
            }
            wA0[p][mt] = f0;
            {
                const f32x4 lo = *(const f32x4*)&w1p[p][ch*32 + 8*q];
                const f32x4 hi = *(const f32x4*)&w1p[p][ch*32 + 8*q + 4];
                bf8 g;
                #pragma unroll
                for (int j = 0; j < 4; ++j) { g[j] = (short)bf_rne(lo[j]); g[4+j] = (short)bf_rne(hi[j]); }
                wA1[p][mt] = g;
            }
            {
                const f32x4 lo = *(const f32x4*)&w2p[p][ch*32 + 8*q];
                const f32x4 hi = *(const f32x4*)&w2p[p][ch*32 + 8*q + 4];
                bf8 g;
                #pragma unroll
                for (int j = 0; j < 4; ++j) { g[j] = (short)bf_rne(lo[j]); g[4+j] = (short)bf_rne(hi[j]); }
                wA2[p][mt] = g;
            }
            {
                const f32x4 bv = *(const f32x4*)&b1p[p][8*q + 4*mt];
                bp1[p][mt][0] = (bf_rne(bv[1]) << 16) | bf_rne(bv[0]);
                bp1[p][mt][1] = (bf_rne(bv[3]) << 16) | bf_rne(bv[2]);
            }
            {
                const f32x4 bv = *(const f32x4*)&b2p[p][8*q + 4*mt];
                bp2[p][mt][0] = (bf_rne(bv[1]) << 16) | bf_rne(bv[0]);
                bp2[p][mt][1] = (bf_rne(bv[3]) << 16) | bf_rne(bv[2]);
            }
            {
                const f32x4 wv3 = *(const f32x4*)&w3p[p][8*q + 4*mt];
                #pragma unroll
                for (int r = 0; r < 4; ++r) w3v[p][mt*4 + r] = wv3[r];
            }
        }
        b3v[p] = b3p[p][0];
    }

    const int img = blockIdx.y;
    const float* __restrict__ X = x + (size_t)img * RES;
    const int wbase = blockIdx.x * PXB + wv * PXW;
    const int i   = wbase >> 9;          // wave-uniform row
    const int jb0 = wbase & (WW - 1);    // 0 or 256

    // per-lane byte offsets of the 8 patch elements at tile 0 (valid on fast path)
    int koff[8];
    #pragma unroll
    for (int j = 0; j < 8; ++j) {
        const int k = 8*q + j;
        int row, col;
        if (k < 21)      { row = i - 3 + k/7; col = jb0 + m16 - 3 + k%7; }
        else if (k < 24) { row = i;           col = jb0 + m16 - 3 + (k - 21); }
        else             { row = i;           col = jb0 + m16; }
        koff[j] = (row*WW + col) * 4;
    }
    int xoff = (i*WW + jb0 + m16) * 4;
    const bool rowsafe = (i >= 3);

    float sx = 0.0f, sd = 0.0f;

    #pragma unroll 1
    for (int u = 0; u < 8; ++u) {
        const int t0 = 2*u, t1 = 2*u + 1;
        bf8 pf0, pf1;
        // fast iff no bounds checks needed for either tile (wave-uniform)
        const bool fast = rowsafe && (jb0 + 16*t0 >= 3) && (jb0 + 16*t1 <= 493);
        if (fast) {
            bf8u r0, r1;
            if (q < 3) {
                float f0[8], f1[8];
                #pragma unroll
                for (int j = 0; j < 8; ++j) {
                    f0[j] = *(const float*)((const char*)X + koff[j]);
                    f1[j] = *(const float*)((const char*)X + koff[j] + 64);
                }
                r0.u[0] = pk2(f0[0], f0[1]); r0.u[1] = pk2(f0[2], f0[3]);
                r0.u[2] = pk2(f0[4], f0[5]); r0.u[3] = pk2(f0[6], f0[7]);
                r1.u[0] = pk2(f1[0], f1[1]); r1.u[1] = pk2(f1[2], f1[3]);
                r1.u[2] = pk2(f1[4], f1[5]); r1.u[3] = pk2(f1[6], f1[7]);
            } else {
                r0.u[0] = 0x00003f80u; r0.u[1] = 0u; r0.u[2] = 0u; r0.u[3] = 0u;
                r1.u[0] = 0x00003f80u; r1.u[1] = 0u; r1.u[2] = 0u; r1.u[3] = 0u;
            }
            pf0 = r0.f; pf1 = r1.f;
        } else {
            pf0 = slow_build(X, i, jb0 + 16*t0, m16, q);
            pf1 = slow_build(X, i, jb0 + 16*t1, m16, q);
        }
        const float xv0 = *(const float*)((const char*)X + xoff);
        const float xv1 = *(const float*)((const char*)X + xoff + 64);

        float pr0[3], pr1[3];
        #pragma unroll
        for (int p = 0; p < 3; ++p) {
            const f32x4 z = {0.f, 0.f, 0.f, 0.f};
            f32x4 a00 = MFMA(wA0[p][0], pf0, z);
            f32x4 a01 = MFMA(wA0[p][1], pf0, z);
            f32x4 a10 = MFMA(wA0[p][0], pf1, z);
            f32x4 a11 = MFMA(wA0[p][1], pf1, z);
            bf8 h0 = actfrag(a00, a01);
            bf8 h1 = actfrag(a10, a11);
            const f32x4 c10 = bias_init(bp1[p][0][0], bp1[p][0][1]);
            const f32x4 c11 = bias_init(bp1[p][1][0], bp1[p][1][1]);
            a00 = MFMA(wA1[p][0], h0, c10);
            a01 = MFMA(wA1[p][1], h0, c11);
            a10 = MFMA(wA1[p][0], h1, c10);
            a11 = MFMA(wA1[p][1], h1, c11);
            h0 = actfrag(a00, a01);
            h1 = actfrag(a10, a11);
            const f32x4 c20 = bias_init(bp2[p][0][0], bp2[p][0][1]);
            const f32x4 c21 = bias_init(bp2[p][1][0], bp2[p][1][1]);
            a00 = MFMA(wA2[p][0], h0, c20);
            a01 = MFMA(wA2[p][1], h0, c21);
            a10 = MFMA(wA2[p][0], h1, c20);
            a11 = MFMA(wA2[p][1], h1, c21);
            float d0 = 0.0f, d1 = 0.0f;
            #pragma unroll
            for (int r = 0; r < 4; ++r) {
                d0 += w3v[p][r]   * lk(a00[r]);
                d0 += w3v[p][4+r] * lk(a01[r]);
                d1 += w3v[p][r]   * lk(a10[r]);
                d1 += w3v[p][4+r] * lk(a11[r]);
            }
            d0 += __shfl_xor(d0, 16);
            d0 += __shfl_xor(d0, 32);
            d1 += __shfl_xor(d1, 16);
            d1 += __shfl_xor(d1, 32);
            pr0[p] = fminf(fmaxf(d0 + b3v[p], -1.0f), 1.0f);
            pr1[p] = fminf(fmaxf(d1 + b3v[p], -1.0f), 1.0f);
        }

        // inline stats, one lane-group per pixel
        if (q == 0) {
            {
                const float med = fmaxf(fminf(pr0[0], fmaxf(pr0[1], pr0[2])), fminf(pr0[1], pr0[2]));
                const float delta = fmodf(xv0 - med + 1.0f, 2.0f) - 1.0f;
                int bx = (int)floorf((xv0 + 1.0f) * 128.0f);
                bx = bx < 0 ? 0 : (bx > 255 ? 255 : bx);
                if (xv0 >= -1.0f && xv0 <= 1.0f) atomicAdd(&shx[bx], 1u);
                int bd = (int)floorf((delta + 1.0f) * 128.0f);
                bd = bd < 0 ? 0 : (bd > 255 ? 255 : bd);
                if (delta >= -1.0f && delta <= 1.0f) atomicAdd(&shd[bd], 1u);
                sx += xv0*xv0; sd += delta*delta;
            }
            {
                const float med = fmaxf(fminf(pr1[0], fmaxf(pr1[1], pr1[2])), fminf(pr1[1], pr1[2]));
                const float delta = fmodf(xv1 - med + 1.0f, 2.0f) - 1.0f;
                int bx = (int)floorf((xv1 + 1.0f) * 128.0f);
                bx = bx < 0 ? 0 : (bx > 255 ? 255 : bx);
                if (xv1 >= -1.0f && xv1 <= 1.0f) atomicAdd(&shx[bx], 1u);
                int bd = (int)floorf((delta + 1.0f) * 128.0f);
                bd = bd < 0 ? 0 : (bd > 255 ? 255 : bd);
                if (delta >= -1.0f && delta <= 1.0f) atomicAdd(&shd[bd], 1u);
                sx += xv1*xv1; sd += delta*delta;
            }
        }

        #pragma unroll
        for (int j = 0; j < 8; ++j) koff[j] += 128;
        xoff += 128;
    }

    // ---- block reduction ----
    #pragma unroll
    for (int off = 32; off > 0; off >>= 1) {
        sx += __shfl_down(sx, off);
        sd += __shfl_down(sd, off);
    }
    if (lane == 0) { red[wv] = sx; red[4 + wv] = sd; }
    __syncthreads();
    if (tid == 0) {
        atomicAdd(&sums[0], red[0] + red[1] + red[2] + red[3]);
        atomicAdd(&sums[1], red[4] + red[5] + red[6] + red[7]);
    }
    if (shx[tid]) atomicAdd(&hist_x[img*NBINS + tid], shx[tid]);
    if (shd[tid]) atomicAdd(&hist_d[img*NBINS + tid], shd[tid]);
}

__global__ __launch_bounds__(256) void codec_final(
    const float* __restrict__ sums,
    const unsigned* __restrict__ hist_x,
    const unsigned* __restrict__ hist_d,
    float* __restrict__ out)
{
    __shared__ float red[16];
    const int tid = threadIdx.x;
    float ex = 0.0f, ed = 0.0f;
    const float inv_res = 1.0f / (float)RES;
    for (int k = tid; k < NIMG*NBINS; k += 256) {
        const unsigned hx = hist_x[k];
        const unsigned hd = hist_d[k];
        if (hx) { const float p = (float)hx * inv_res; ex -= p * log2f(p); }
        if (hd) { const float p = (float)hd * inv_res; ed -= p * log2f(p); }
    }
    #pragma unroll
    for (int off = 32; off > 0; off >>= 1) {
        ex += __shfl_down(ex, off);
        ed += __shfl_down(ed, off);
    }
    const int lane = tid & 63, wv = tid >> 6;
    if (lane == 0) { red[wv] = ex; red[8 + wv] = ed; }
    __syncthreads();
    if (tid == 0) {
        const float Ex = red[0] + red[1] + red[2] + red[3];
        const float Ed = red[8] + red[9] + red[10] + red[11];
        const float inv_n = 1.0f / (float)(NIMG * RES);
        out[0] = 255.0f * sqrtf(sums[1] * inv_n);   // loss1 (deltas)
        out[1] = 255.0f * sqrtf(sums[0] * inv_n);   // loss0 (x)
        out[2] = Ex / (8.0f * (float)NIMG);         // invCR0
        out[3] = Ed / (8.0f * (float)NIMG);         // invCR1
    }
}

extern "C" void kernel_launch(void* const* d_in, const int* in_sizes, int n_in,
                              void* d_out, int out_size, void* d_ws, size_t ws_size,
                              hipStream_t stream)
{
    const float* x = (const float*)d_in[0];
    const float* w[27];
    for (int k = 0; k < 27; ++k) w[k] = (const float*)d_in[1 + k];

    float*    sums   = (float*)d_ws;
    unsigned* hist_x = (unsigned*)((char*)d_ws + 16);
    unsigned* hist_d = hist_x + NIMG*NBINS;
    const size_t zbytes = 16 + (size_t)2*NIMG*NBINS*sizeof(unsigned);
    hipMemsetAsync(d_ws, 0, zbytes, stream);

    dim3 grid(RES/PXB, NIMG);
    codec_main<<<grid, dim3(256), 0, stream>>>(
        x,
        w[0],  w[1],  w[2],  w[3],  w[4],  w[5],  w[6],  w[7],  w[8],
        w[9],  w[10], w[11], w[12], w[13], w[14], w[15], w[16], w[17],
        w[18], w[19], w[20], w[21], w[22], w[23], w[24], w[25], w[26],
        sums, hist_x, hist_d);
    codec_final<<<1, dim3(256), 0, stream>>>(sums, hist_x, hist_d, (float*)d_out);
}

// Round 7
// 459.375 us; speedup vs baseline: 10.7168x; 1.0444x over previous
//
#include <hip/hip_runtime.h>
#include <hip/hip_bf16.h>
#include <cmath>

#define HH 512
#define WW 512
#define NIMG 12
#define RES (HH*WW)
#define NBINS 256
#define PXB 1024            // pixels per block (4 waves)
#define PXW 256             // pixels per wave = half an image row

typedef __attribute__((ext_vector_type(8))) short bf8;     // 8 bf16 (4 VGPR) MFMA A/B frag
typedef __attribute__((ext_vector_type(4))) float f32x4;   // MFMA C/D frag

__device__ __forceinline__ unsigned bf_rne(float x) {      // f32 -> bf16 bits (setup/edge path)
    unsigned u = __float_as_uint(x);
    return (u + 0x7fffu + ((u >> 16) & 1u)) >> 16;
}

__device__ __forceinline__ unsigned pk2(float a, float b) { // packed f32x2 -> bf16x2
    float2 t; t.x = a; t.y = b;
    union { __hip_bfloat162 h; unsigned u; } c;
    c.h = __float22bfloat162_rn(t);
    return c.u;
}

union bf8u { bf8 f; unsigned u[4]; };

// raw C/D frag pair -> bf16 B frag (no activation; sigma-permuted rows make layout line up)
__device__ __forceinline__ bf8 cvtfrag(const f32x4 a0, const f32x4 a1) {
    bf8u r;
    r.u[0] = pk2(a0[0], a0[1]);
    r.u[1] = pk2(a0[2], a0[3]);
    r.u[2] = pk2(a1[0], a1[1]);
    r.u[3] = pk2(a1[2], a1[3]);
    return r.f;
}
// |frag| : clear bf16 sign bits, exact
__device__ __forceinline__ bf8 absfrag(const bf8 v) {
    bf8u r; r.f = v;
    r.u[0] &= 0x7fff7fffu; r.u[1] &= 0x7fff7fffu;
    r.u[2] &= 0x7fff7fffu; r.u[3] &= 0x7fff7fffu;
    return r.f;
}

// edge-tile patch builder with full bounds checks (rare path)
__device__ __forceinline__ bf8 slow_build(const float* __restrict__ X,
                                          int i, int jb, int m16, int q)
{
    const int jc = jb + m16;
    bf8 pf;
    #pragma unroll
    for (int j = 0; j < 8; ++j) {
        const int k = 8*q + j;
        float v = 0.0f;
        if (k < 21) {
            const int rr = i - 3 + k/7;
            const int cc = jc - 3 + k%7;
            if (rr >= 0 && cc >= 0 && cc < WW) v = X[rr*WW + cc];
        } else if (k < 24) {
            const int cc = jc - 3 + (k - 21);
            if (cc >= 0) v = X[i*WW + cc];
        } else if (k == 24) {
            v = 1.0f;
        }
        pf[j] = (short)bf_rne(v);
    }
    return pf;
}

#define MFMA(A, B, C) __builtin_amdgcn_mfma_f32_16x16x32_bf16((A), (B), (C), 0, 0, 0)

// full MLP for one predictor on one 16-px tile; leaky-relu folded into
// raw/abs weight pairs (lk(z) = 0.505 z + 0.495 |z|, exact).
__device__ __forceinline__ void run_pred_tile(
    const bf8 w0a, const bf8 w0b,
    const bf8 w1r0, const bf8 w1a0, const bf8 w1r1, const bf8 w1a1,
    const bf8 w2r0, const bf8 w2a0, const bf8 w2r1, const bf8 w2a1,
    const bf8 w3r, const bf8 w3a,
    const f32x4 c10, const f32x4 c11, const f32x4 c20, const f32x4 c21,
    const bf8 pf, f32x4& acc3)
{
    const f32x4 z = {0.f, 0.f, 0.f, 0.f};
    f32x4 za = MFMA(w0a, pf, z);
    f32x4 zb = MFMA(w0b, pf, z);
    bf8 zr = cvtfrag(za, zb);
    bf8 zm = absfrag(zr);
    za = MFMA(w1r0, zr, c10); za = MFMA(w1a0, zm, za);
    zb = MFMA(w1r1, zr, c11); zb = MFMA(w1a1, zm, zb);
    zr = cvtfrag(za, zb);
    zm = absfrag(zr);
    za = MFMA(w2r0, zr, c20); za = MFMA(w2a0, zm, za);
    zb = MFMA(w2r1, zr, c21); zb = MFMA(w2a1, zm, zb);
    zr = cvtfrag(za, zb);
    zm = absfrag(zr);
    acc3 = MFMA(w3r, zr, acc3);
    acc3 = MFMA(w3a, zm, acc3);
}

__global__ __launch_bounds__(256, 2) void codec_main(
    const float* __restrict__ x,
    const float* __restrict__ a_wT, const float* __restrict__ a_bT, const float* __restrict__ a_wL,
    const float* __restrict__ a_w1, const float* __restrict__ a_b1,
    const float* __restrict__ a_w2, const float* __restrict__ a_b2,
    const float* __restrict__ a_w3, const float* __restrict__ a_b3,
    const float* __restrict__ b_wT, const float* __restrict__ b_bT, const float* __restrict__ b_wL,
    const float* __restrict__ b_w1, const float* __restrict__ b_b1,
    const float* __restrict__ b_w2, const float* __restrict__ b_b2,
    const float* __restrict__ b_w3, const float* __restrict__ b_b3,
    const float* __restrict__ c_wT, const float* __restrict__ c_bT, const float* __restrict__ c_wL,
    const float* __restrict__ c_w1, const float* __restrict__ c_b1,
    const float* __restrict__ c_w2, const float* __restrict__ c_b2,
    const float* __restrict__ c_w3, const float* __restrict__ c_b3,
    float* __restrict__ sums,
    unsigned* __restrict__ hist_x,
    unsigned* __restrict__ hist_d)
{
    __shared__ unsigned shx[NBINS], shd[NBINS];
    __shared__ float red[8];
    __shared__ __align__(16) float blds[3][2][2][4][4];   // [pred][layer12][mt][q][4]

    const int tid  = threadIdx.x;
    const int lane = tid & 63;
    const int wv   = tid >> 6;
    const int q    = lane >> 4;     // quad group: k = 8q+j (A/B), rows 4q+r (C/D)
    const int m16  = lane & 15;     // m (A) / n=pixel (B, C/D)

    shx[tid] = 0u; shd[tid] = 0u;

    const float* wTp[3] = {a_wT, b_wT, c_wT};
    const float* bTp[3] = {a_bT, b_bT, c_bT};
    const float* wLp[3] = {a_wL, b_wL, c_wL};
    const float* w1p[3] = {a_w1, b_w1, c_w1};
    const float* b1p[3] = {a_b1, b_b1, c_b1};
    const float* w2p[3] = {a_w2, b_w2, c_w2};
    const float* b2p[3] = {a_b2, b_b2, c_b2};
    const float* w3p[3] = {a_w3, b_w3, c_w3};
    const float* b3p[3] = {a_b3, b_b3, c_b3};

    // biases (f32, exact) -> LDS; 48 f32x4 entries
    if (tid < 48) {
        const int e = tid;
        const int p = e >> 4, ly = (e >> 3) & 1, mt = (e >> 2) & 1, qq = e & 3;
        const float* src = (ly == 0 ? b1p[p] : b2p[p]) + 8*qq + 4*mt;
        *(f32x4*)&blds[p][ly][mt][qq][0] = *(const f32x4*)src;
    }

    // ---- one-time: weights -> MFMA A-frags (rows sigma-permuted), with
    // 0.505/0.495-scaled raw/abs copies for folded leaky-relu ----
    bf8 wA0[3][2], wA1r[3][2], wA1a[3][2], wA2r[3][2], wA2a[3][2];
    bf8 aw3r[3], aw3a[3];
    #pragma unroll
    for (int p = 0; p < 3; ++p) {
        #pragma unroll
        for (int mt = 0; mt < 2; ++mt) {
            const int ch = ((m16 >> 2) << 3) + (mt << 2) + (m16 & 3);   // sigma(16mt+m16)
            bf8 f0;
            #pragma unroll
            for (int j = 0; j < 8; ++j) {
                const int k = 8*q + j;
                float v = 0.0f;
                if (k < 21)       v = wTp[p][ch*21 + k];
                else if (k < 24)  v = wLp[p][ch*3 + (k - 21)];
                else if (k == 24) v = bTp[p][ch];
                f0[j] = (short)bf_rne(v);
            }
            wA0[p][mt] = f0;
            {
                const f32x4 lo = *(const f32x4*)&w1p[p][ch*32 + 8*q];
                const f32x4 hi = *(const f32x4*)&w1p[p][ch*32 + 8*q + 4];
                bf8 gr, ga;
                #pragma unroll
                for (int j = 0; j < 4; ++j) {
                    gr[j]   = (short)bf_rne(0.505f*lo[j]); gr[4+j] = (short)bf_rne(0.505f*hi[j]);
                    ga[j]   = (short)bf_rne(0.495f*lo[j]); ga[4+j] = (short)bf_rne(0.495f*hi[j]);
                }
                wA1r[p][mt] = gr; wA1a[p][mt] = ga;
            }
            {
                const f32x4 lo = *(const f32x4*)&w2p[p][ch*32 + 8*q];
                const f32x4 hi = *(const f32x4*)&w2p[p][ch*32 + 8*q + 4];
                bf8 gr, ga;
                #pragma unroll
                for (int j = 0; j < 4; ++j) {
                    gr[j]   = (short)bf_rne(0.505f*lo[j]); gr[4+j] = (short)bf_rne(0.505f*hi[j]);
                    ga[j]   = (short)bf_rne(0.495f*lo[j]); ga[4+j] = (short)bf_rne(0.495f*hi[j]);
                }
                wA2r[p][mt] = gr; wA2a[p][mt] = ga;
            }
        }
        // L3 A-frags: w3_p in row p only (columns natural: sigma fixed-point)
        {
            bf8 gr, ga;
            #pragma unroll
            for (int j = 0; j < 8; ++j) {
                const float v = (m16 == p) ? w3p[p][8*q + j] : 0.0f;
                gr[j] = (short)bf_rne(0.505f*v);
                ga[j] = (short)bf_rne(0.495f*v);
            }
            aw3r[p] = gr; aw3a[p] = ga;
        }
    }
    // L3 bias as C-init: row r (<3) = b3 of predictor r
    f32x4 bias3v = {0.f, 0.f, 0.f, 0.f};
    if (q == 0) { bias3v[0] = b3p[0][0]; bias3v[1] = b3p[1][0]; bias3v[2] = b3p[2][0]; }

    __syncthreads();

    const int img = blockIdx.y;
    const float* __restrict__ X = x + (size_t)img * RES;
    const int wbase = blockIdx.x * PXB + wv * PXW;
    const int i   = wbase >> 9;          // wave-uniform row
    const int jb0 = wbase & (WW - 1);    // 0 or 256

    int koff[8];
    #pragma unroll
    for (int j = 0; j < 8; ++j) {
        const int k = 8*q + j;
        int row, col;
        if (k < 21)      { row = i - 3 + k/7; col = jb0 + m16 - 3 + k%7; }
        else if (k < 24) { row = i;           col = jb0 + m16 - 3 + (k - 21); }
        else             { row = i;           col = jb0 + m16; }
        koff[j] = (row*WW + col) * 4;
    }
    int xoff = (i*WW + jb0 + m16) * 4;
    const bool rowsafe = (i >= 3);

    float sx = 0.0f, sd = 0.0f;

    #pragma unroll 1
    for (int u = 0; u < 8; ++u) {
        const int t0 = 2*u, t1 = 2*u + 1;
        bf8 pf0, pf1;
        const bool fast = rowsafe && (jb0 + 16*t0 >= 3) && (jb0 + 16*t1 <= 493);
        if (fast) {
            bf8u r0, r1;
            if (q < 3) {
                float f0[8], f1[8];
                #pragma unroll
                for (int j = 0; j < 8; ++j) {
                    f0[j] = *(const float*)((const char*)X + koff[j]);
                    f1[j] = *(const float*)((const char*)X + koff[j] + 64);
                }
                r0.u[0] = pk2(f0[0], f0[1]); r0.u[1] = pk2(f0[2], f0[3]);
                r0.u[2] = pk2(f0[4], f0[5]); r0.u[3] = pk2(f0[6], f0[7]);
                r1.u[0] = pk2(f1[0], f1[1]); r1.u[1] = pk2(f1[2], f1[3]);
                r1.u[2] = pk2(f1[4], f1[5]); r1.u[3] = pk2(f1[6], f1[7]);
            } else {
                r0.u[0] = 0x00003f80u; r0.u[1] = 0u; r0.u[2] = 0u; r0.u[3] = 0u;
                r1.u[0] = 0x00003f80u; r1.u[1] = 0u; r1.u[2] = 0u; r1.u[3] = 0u;
            }
            pf0 = r0.f; pf1 = r1.f;
        } else {
            pf0 = slow_build(X, i, jb0 + 16*t0, m16, q);
            pf1 = slow_build(X, i, jb0 + 16*t1, m16, q);
        }
        const float xv0 = *(const float*)((const char*)X + xoff);
        const float xv1 = *(const float*)((const char*)X + xoff + 64);

        f32x4 acc30 = bias3v;     // tile0: all 3 preds in rows 0..2
        f32x4 acc31 = bias3v;     // tile1
        #pragma unroll
        for (int p = 0; p < 3; ++p) {
            const f32x4 c10 = *(const f32x4*)&blds[p][0][0][q][0];
            const f32x4 c11 = *(const f32x4*)&blds[p][0][1][q][0];
            const f32x4 c20 = *(const f32x4*)&blds[p][1][0][q][0];
            const f32x4 c21 = *(const f32x4*)&blds[p][1][1][q][0];
            run_pred_tile(wA0[p][0], wA0[p][1],
                          wA1r[p][0], wA1a[p][0], wA1r[p][1], wA1a[p][1],
                          wA2r[p][0], wA2a[p][0], wA2r[p][1], wA2a[p][1],
                          aw3r[p], aw3a[p], c10, c11, c20, c21, pf0, acc30);
            run_pred_tile(wA0[p][0], wA0[p][1],
                          wA1r[p][0], wA1a[p][0], wA1r[p][1], wA1a[p][1],
                          wA2r[p][0], wA2a[p][0], wA2r[p][1], wA2a[p][1],
                          aw3r[p], aw3a[p], c10, c11, c20, c21, pf1, acc31);
        }

        // stats: q==0 lanes hold preds a,b,c in acc3 regs 0..2 for pixel m16
        if (q == 0) {
            {
                const float pa = fminf(fmaxf(acc30[0], -1.0f), 1.0f);
                const float pb = fminf(fmaxf(acc30[1], -1.0f), 1.0f);
                const float pc = fminf(fmaxf(acc30[2], -1.0f), 1.0f);
                const float med = fmaxf(fminf(pa, fmaxf(pb, pc)), fminf(pb, pc));
                const float delta = fmodf(xv0 - med + 1.0f, 2.0f) - 1.0f;
                int bx = (int)floorf((xv0 + 1.0f) * 128.0f);
                bx = bx < 0 ? 0 : (bx > 255 ? 255 : bx);
                if (xv0 >= -1.0f && xv0 <= 1.0f) atomicAdd(&shx[bx], 1u);
                int bd = (int)floorf((delta + 1.0f) * 128.0f);
                bd = bd < 0 ? 0 : (bd > 255 ? 255 : bd);
                if (delta >= -1.0f && delta <= 1.0f) atomicAdd(&shd[bd], 1u);
                sx += xv0*xv0; sd += delta*delta;
            }
            {
                const float pa = fminf(fmaxf(acc31[0], -1.0f), 1.0f);
                const float pb = fminf(fmaxf(acc31[1], -1.0f), 1.0f);
                const float pc = fminf(fmaxf(acc31[2], -1.0f), 1.0f);
                const float med = fmaxf(fminf(pa, fmaxf(pb, pc)), fminf(pb, pc));
                const float delta = fmodf(xv1 - med + 1.0f, 2.0f) - 1.0f;
                int bx = (int)floorf((xv1 + 1.0f) * 128.0f);
                bx = bx < 0 ? 0 : (bx > 255 ? 255 : bx);
                if (xv1 >= -1.0f && xv1 <= 1.0f) atomicAdd(&shx[bx], 1u);
                int bd = (int)floorf((delta + 1.0f) * 128.0f);
                bd = bd < 0 ? 0 : (bd > 255 ? 255 : bd);
                if (delta >= -1.0f && delta <= 1.0f) atomicAdd(&shd[bd], 1u);
                sx += xv1*xv1; sd += delta*delta;
            }
        }

        #pragma unroll
        for (int j = 0; j < 8; ++j) koff[j] += 128;
        xoff += 128;
    }

    // ---- block reduction ----
    #pragma unroll
    for (int off = 32; off > 0; off >>= 1) {
        sx += __shfl_down(sx, off);
        sd += __shfl_down(sd, off);
    }
    if (lane == 0) { red[wv] = sx; red[4 + wv] = sd; }
    __syncthreads();
    if (tid == 0) {
        atomicAdd(&sums[0], red[0] + red[1] + red[2] + red[3]);
        atomicAdd(&sums[1], red[4] + red[5] + red[6] + red[7]);
    }
    if (shx[tid]) atomicAdd(&hist_x[img*NBINS + tid], shx[tid]);
    if (shd[tid]) atomicAdd(&hist_d[img*NBINS + tid], shd[tid]);
}

__global__ __launch_bounds__(256) void codec_final(
    const float* __restrict__ sums,
    const unsigned* __restrict__ hist_x,
    const unsigned* __restrict__ hist_d,
    float* __restrict__ out)
{
    __shared__ float red[16];
    const int tid = threadIdx.x;
    float ex = 0.0f, ed = 0.0f;
    const float inv_res = 1.0f / (float)RES;
    for (int k = tid; k < NIMG*NBINS; k += 256) {
        const unsigned hx = hist_x[k];
        const unsigned hd = hist_d[k];
        if (hx) { const float p = (float)hx * inv_res; ex -= p * log2f(p); }
        if (hd) { const float p = (float)hd * inv_res; ed -= p * log2f(p); }
    }
    #pragma unroll
    for (int off = 32; off > 0; off >>= 1) {
        ex += __shfl_down(ex, off);
        ed += __shfl_down(ed, off);
    }
    const int lane = tid & 63, wv = tid >> 6;
    if (lane == 0) { red[wv] = ex; red[8 + wv] = ed; }
    __syncthreads();
    if (tid == 0) {
        const float Ex = red[0] + red[1] + red[2] + red[3];
        const float Ed = red[8] + red[9] + red[10] + red[11];
        const float inv_n = 1.0f / (float)(NIMG * RES);
        out[0] = 255.0f * sqrtf(sums[1] * inv_n);   // loss1 (deltas)
        out[1] = 255.0f * sqrtf(sums[0] * inv_n);   // loss0 (x)
        out[2] = Ex / (8.0f * (float)NIMG);         // invCR0
        out[3] = Ed / (8.0f * (float)NIMG);         // invCR1
    }
}

extern "C" void kernel_launch(void* const* d_in, const int* in_sizes, int n_in,
                              void* d_out, int out_size, void* d_ws, size_t ws_size,
                              hipStream_t stream)
{
    const float* x = (const float*)d_in[0];
    const float* w[27];
    for (int k = 0; k < 27; ++k) w[k] = (const float*)d_in[1 + k];

    float*    sums   = (float*)d_ws;
    unsigned* hist_x = (unsigned*)((char*)d_ws + 16);
    unsigned* hist_d = hist_x + NIMG*NBINS;
    const size_t zbytes = 16 + (size_t)2*NIMG*NBINS*sizeof(unsigned);
    hipMemsetAsync(d_ws, 0, zbytes, stream);

    dim3 grid(RES/PXB, NIMG);
    codec_main<<<grid, dim3(256), 0, stream>>>(
        x,
        w[0],  w[1],  w[2],  w[3],  w[4],  w[5],  w[6],  w[7],  w[8],
        w[9],  w[10], w[11], w[12], w[13], w[14], w[15], w[16], w[17],
        w[18], w[19], w[20], w[21], w[22], w[23], w[24], w[25], w[26],
        sums, hist_x, hist_d);
    codec_final<<<1, dim3(256), 0, stream>>>(sums, hist_x, hist_d, (float*)d_out);
}